// Round 3
// baseline (229.236 us; speedup 1.0000x reference)
//
#include <hip/hip_runtime.h>

#define NP     8732   // priors
#define NB     32     // batch
#define NOBJ   16     // truths per image
#define NC     81     // classes
#define CHUNKS 32
#define CHUNK  ((NP + CHUNKS - 1) / CHUNKS)   // 273
#define RPB    128                            // rows per kce block
#define NROWS  (NB * NP)                      // 279424 = 2183 * 128 exactly
#define CE_BLOCKS (NROWS / RPB)               // 2183

__device__ __forceinline__ float sl1(float x) {
  float d = fabsf(x);
  return d < 1.0f ? 0.5f * d * d : d - 0.5f;
}

// ---- Kernel A1: per-truth best prior per chunk (plain stores, no init needed) ----
__global__ __launch_bounds__(256) void kbestprior(
    const float* __restrict__ targets, const float* __restrict__ priors,
    unsigned long long* __restrict__ bestPrChunk, int* __restrict__ zero_region)
{
  const int b   = blockIdx.y;
  const int ch  = blockIdx.x;
  const int p0  = ch * CHUNK;
  const int p1  = min(NP, p0 + CHUNK);
  const int tid = threadIdx.x;

  // zero the accumulator region (facc/iacc/num_pos) -- consumers run in later kernels
  if (ch == 0 && b == 0 && tid < 64) zero_region[tid] = 0;

  __shared__ float tx0[NOBJ], ty0[NOBJ], tx1[NOBJ], ty1[NOBJ], tarea[NOBJ];
  __shared__ unsigned long long sbest[NOBJ];

  if (tid < NOBJ) {
    const float* tg = targets + (b * NOBJ + tid) * 5;
    float x0 = tg[0], y0 = tg[1], x1 = tg[2], y1 = tg[3];
    tx0[tid] = x0; ty0[tid] = y0; tx1[tid] = x1; ty1[tid] = y1;
    tarea[tid] = (x1 - x0) * (y1 - y0);
    sbest[tid] = 0ull;
  }
  __syncthreads();

  float bv[NOBJ]; int bp[NOBJ];
  #pragma unroll
  for (int n = 0; n < NOBJ; ++n) { bv[n] = -1.0f; bp[n] = 0; }

  for (int p = p0 + tid; p < p1; p += 256) {
    float4 pr = reinterpret_cast<const float4*>(priors)[p];
    float px0 = pr.x - pr.z * 0.5f;
    float py0 = pr.y - pr.w * 0.5f;
    float px1 = pr.x + pr.z * 0.5f;
    float py1 = pr.y + pr.w * 0.5f;
    float parea = (px1 - px0) * (py1 - py0);
    #pragma unroll
    for (int n = 0; n < NOBJ; ++n) {
      float w = fminf(tx1[n], px1) - fmaxf(tx0[n], px0);
      float h = fminf(ty1[n], py1) - fmaxf(ty0[n], py0);
      w = fmaxf(w, 0.0f); h = fmaxf(h, 0.0f);
      float inter = w * h;
      float iou = inter / (tarea[n] + parea - inter);
      if (iou > bv[n]) { bv[n] = iou; bp[n] = p; }   // first occurrence: strict >
    }
  }
  // pack (iou_bits, NP - p): equal iou -> smaller p wins (first occurrence)
  #pragma unroll
  for (int n = 0; n < NOBJ; ++n) {
    unsigned long long key = (bv[n] < 0.0f) ? 0ull :
        (((unsigned long long)__float_as_uint(bv[n]) << 32) | (unsigned)(NP - bp[n]));
    #pragma unroll
    for (int s = 1; s < 64; s <<= 1) {
      unsigned long long o = __shfl_xor(key, s, 64);
      key = (o > key) ? o : key;
    }
    if ((tid & 63) == 0) atomicMax(&sbest[n], key);
  }
  __syncthreads();
  if (tid < NOBJ)
    bestPrChunk[(b * NOBJ + tid) * CHUNKS + ch] = sbest[tid];
}

// ---- Kernel A2: assignment + localization loss ----
__global__ __launch_bounds__(256) void kassign(
    const float* __restrict__ loc, const float* __restrict__ targets,
    const float* __restrict__ priors,
    const unsigned long long* __restrict__ bestPrChunk,
    int* __restrict__ conf_t, int* __restrict__ num_pos,
    float* __restrict__ facc, int* __restrict__ iacc)
{
  const int b   = blockIdx.y;
  const int p0  = blockIdx.x * CHUNK;
  const int p1  = min(NP, p0 + CHUNK);
  const int tid = threadIdx.x;
  __shared__ float tx0[NOBJ], ty0[NOBJ], tx1[NOBJ], ty1[NOBJ], tarea[NOBJ];
  __shared__ int tlab[NOBJ], decP[NOBJ];
  __shared__ float redf[4];
  __shared__ int   redi[4];

  if (tid < NOBJ) {
    const float* tg = targets + (b * NOBJ + tid) * 5;
    float x0 = tg[0], y0 = tg[1], x1 = tg[2], y1 = tg[3];
    tx0[tid] = x0; ty0[tid] = y0; tx1[tid] = x1; ty1[tid] = y1;
    tarea[tid] = (x1 - x0) * (y1 - y0);
    tlab[tid] = (int)tg[4];
    const unsigned long long* kp = bestPrChunk + (b * NOBJ + tid) * CHUNKS;
    unsigned long long key = 0ull;
    #pragma unroll
    for (int c = 0; c < CHUNKS; ++c) {
      unsigned long long o = kp[c];
      key = (o > key) ? o : key;
    }
    decP[tid] = NP - (int)(key & 0xFFFFFFFFull);
  }
  __syncthreads();

  float lsum = 0.0f; int pcnt = 0;
  for (int p = p0 + tid; p < p1; p += 256) {
    float4 pr = reinterpret_cast<const float4*>(priors)[p];
    float px0 = pr.x - pr.z * 0.5f;
    float py0 = pr.y - pr.w * 0.5f;
    float px1 = pr.x + pr.z * 0.5f;
    float py1 = pr.y + pr.w * 0.5f;
    float parea = (px1 - px0) * (py1 - py0);
    float bestov = -1.0f; int bestn = 0;
    #pragma unroll
    for (int n = 0; n < NOBJ; ++n) {
      float w = fminf(tx1[n], px1) - fmaxf(tx0[n], px0);
      float h = fminf(ty1[n], py1) - fmaxf(ty0[n], py0);
      w = fmaxf(w, 0.0f); h = fmaxf(h, 0.0f);
      float inter = w * h;
      float iou = inter / (tarea[n] + parea - inter);
      if (iou > bestov) { bestov = iou; bestn = n; }  // first occurrence over n
    }
    // forced-match override: sequential last-wins -> the LARGEST n matching p
    #pragma unroll
    for (int n = 0; n < NOBJ; ++n)
      if (decP[n] == p) { bestn = n; bestov = 2.0f; }
    int c = (bestov < 0.5f) ? 0 : (tlab[bestn] + 1);
    conf_t[b * NP + p] = c;
    if (c > 0) {
      ++pcnt;
      int n = bestn;
      float mx0 = tx0[n], my0 = ty0[n], mx1 = tx1[n], my1 = ty1[n];
      float gx = ((mx0 + mx1) * 0.5f - pr.x) / (0.1f * pr.z);
      float gy = ((my0 + my1) * 0.5f - pr.y) / (0.1f * pr.w);
      float gw = logf((mx1 - mx0) / pr.z) / 0.2f;
      float gh = logf((my1 - my0) / pr.w) / 0.2f;
      float4 ld = reinterpret_cast<const float4*>(loc)[b * NP + p];
      lsum += sl1(ld.x - gx) + sl1(ld.y - gy) + sl1(ld.z - gw) + sl1(ld.w - gh);
    }
  }
  #pragma unroll
  for (int s = 32; s >= 1; s >>= 1) {
    lsum += __shfl_xor(lsum, s, 64);
    pcnt += __shfl_xor(pcnt, s, 64);
  }
  if ((tid & 63) == 0) { redf[tid >> 6] = lsum; redi[tid >> 6] = pcnt; }
  __syncthreads();
  if (tid == 0) {
    float lt = redf[0] + redf[1] + redf[2] + redf[3];
    int   pt = redi[0] + redi[1] + redi[2] + redi[3];
    atomicAdd(&num_pos[b], pt);
    atomicAdd(&facc[0], lt);
    atomicAdd(&iacc[0], pt);
  }
}

// ---- Kernel B: per-prior cross entropy, LDS-staged float4 streaming ----
__global__ __launch_bounds__(256) void kce(
    const float* __restrict__ conf, const int* __restrict__ conf_t,
    float* __restrict__ mine, float* __restrict__ facc)
{
  __shared__ float4 buf4[RPB * NC / 4];     // 2592 float4 = 41472 B
  __shared__ float redf[4];
  float* buf = (float*)buf4;
  const int base = blockIdx.x * RPB;
  const float4* src = reinterpret_cast<const float4*>(conf) + (size_t)base * NC / 4;

  // stage 2592 float4s with 256 threads: 10 full strides + partial (32 threads)
  {
    const int t = threadIdx.x;
    float4 tmp[10];
    #pragma unroll
    for (int i = 0; i < 10; ++i) tmp[i] = src[t + i * 256];
    #pragma unroll
    for (int i = 0; i < 10; ++i) buf4[t + i * 256] = tmp[i];
    if (t < 32) buf4[2560 + t] = src[2560 + t];
  }
  __syncthreads();

  const int r = threadIdx.x >> 1;           // row within block: 0..127
  const int h = threadIdx.x & 1;            // half: 0 -> [0,41), 1 -> [41,81)
  const float* rowp = buf + r * NC + h * 41;
  const int cnt = 41 - h;
  float m = -3.0e38f;
  for (int j = 0; j < cnt; ++j) m = fmaxf(m, rowp[j]);
  m = fmaxf(m, __shfl_xor(m, 1, 64));       // pair lanes 2r / 2r+1
  float s = 0.0f;
  for (int j = 0; j < cnt; ++j) s += expf(rowp[j] - m);
  s += __shfl_xor(s, 1, 64);

  float cepos = 0.0f;
  if (h == 0) {
    float lse = m + logf(s);
    int gr = base + r;
    int ct = conf_t[gr];
    float ce = lse - buf[r * NC + ct];
    bool pos = ct > 0;
    mine[gr] = pos ? 0.0f : ce;
    if (pos) cepos = ce;
  }
  #pragma unroll
  for (int sh = 32; sh >= 1; sh >>= 1) cepos += __shfl_xor(cepos, sh, 64);
  if ((threadIdx.x & 63) == 0) redf[threadIdx.x >> 6] = cepos;
  __syncthreads();
  if (threadIdx.x == 0)
    atomicAdd(&facc[1], redf[0] + redf[1] + redf[2] + redf[3]);
}

// ---- Kernel C: exact top-k sum per batch, register-resident values ----
__global__ __launch_bounds__(1024) void ktopk(
    const float* __restrict__ mine, const int* __restrict__ num_pos,
    float* __restrict__ facc)
{
  const int b = blockIdx.x, tid = threadIdx.x;
  const int wid = tid >> 6, lane = tid & 63;
  __shared__ int   redi[2][16];
  __shared__ float redff[16];
  __shared__ int   redii[16];
  const float* src = mine + (size_t)b * NP;

  float rv[9];
  #pragma unroll
  for (int i = 0; i < 9; ++i) {
    int idx = tid + (i << 10);
    rv[i] = (idx < NP) ? src[idx] : -1.0f;   // sentinel: never > thr (thr >= 0)
  }
  int k = 3 * num_pos[b];
  if (k > NP - 1) k = NP - 1;
  if (k <= 0) return;

  // exact k-th largest: min u with count(v > f(u)) < k   (values >= 0)
  unsigned lo = 0u, hi = 0x7f800000u;
  int par = 0;
  while (lo < hi) {
    unsigned mid = lo + ((hi - lo) >> 1);
    float thr = __uint_as_float(mid);
    int c = 0;
    #pragma unroll
    for (int i = 0; i < 9; ++i) c += (rv[i] > thr) ? 1 : 0;
    #pragma unroll
    for (int s = 32; s >= 1; s >>= 1) c += __shfl_xor(c, s, 64);
    if (lane == 0) redi[par][wid] = c;
    __syncthreads();
    int tot = 0;
    #pragma unroll
    for (int w = 0; w < 16; ++w) tot += redi[par][w];   // broadcast reads
    par ^= 1;
    if (tot < k) hi = mid; else lo = mid + 1;
  }
  float vk = __uint_as_float(lo);

  int cgt = 0; float s = 0.0f;
  #pragma unroll
  for (int i = 0; i < 9; ++i) {
    float val = rv[i];
    if (val > vk) { ++cgt; s += val; }
  }
  #pragma unroll
  for (int sh = 32; sh >= 1; sh >>= 1) {
    cgt += __shfl_xor(cgt, sh, 64);
    s   += __shfl_xor(s,   sh, 64);
  }
  __syncthreads();                          // protect redi/redff reuse (WAR)
  if (lane == 0) { redii[wid] = cgt; redff[wid] = s; }
  __syncthreads();
  if (tid == 0) {
    int c = 0; float tot = 0.0f;
    #pragma unroll
    for (int w = 0; w < 16; ++w) { c += redii[w]; tot += redff[w]; }
    tot += (float)(k - c) * vk;
    atomicAdd(&facc[2], tot);
  }
}

// ---- Kernel D: final normalization ----
__global__ void kfinal(const float* __restrict__ facc,
                       const int* __restrict__ iacc, float* __restrict__ out)
{
  float N = (float)iacc[0];
  out[0] = facc[0] / N;                 // LOC_WEIGHT = 1.0
  out[1] = (facc[1] + facc[2]) / N;
}

extern "C" void kernel_launch(void* const* d_in, const int* in_sizes, int n_in,
                              void* d_out, int out_size, void* d_ws, size_t ws_size,
                              hipStream_t stream) {
  const float* loc     = (const float*)d_in[0];
  const float* conf    = (const float*)d_in[1];
  const float* targets = (const float*)d_in[2];
  const float* priors  = (const float*)d_in[3];
  float* out = (float*)d_out;

  // workspace layout (bytes):
  //   [0,16)        float facc[4]   : [0] loss_l  [1] ce_pos  [2] topk
  //   [16,20)       int   iacc      : total positives
  //   [32,160)      int   num_pos[NB]
  //   [256,131328)  u64   bestPrChunk[NB][NOBJ][CHUNKS]
  //   [131584,..)   int   conf_t[NB*NP]
  //   [1249280,..)  float mine[NB*NP]
  char* ws = (char*)d_ws;
  float* facc    = (float*)ws;
  int*   iacc    = (int*)ws + 4;
  int*   num_pos = (int*)ws + 8;
  int*   zero_region = (int*)ws;                       // first 64 ints
  unsigned long long* bestPrChunk = (unsigned long long*)(ws + 256);
  int*   conf_t  = (int*)(ws + 131584);
  float* mine    = (float*)(ws + 1249280);

  hipLaunchKernelGGL(kbestprior, dim3(CHUNKS, NB), dim3(256), 0, stream,
                     targets, priors, bestPrChunk, zero_region);
  hipLaunchKernelGGL(kassign, dim3(CHUNKS, NB), dim3(256), 0, stream,
                     loc, targets, priors, bestPrChunk, conf_t, num_pos, facc, iacc);
  hipLaunchKernelGGL(kce, dim3(CE_BLOCKS), dim3(256), 0, stream,
                     conf, conf_t, mine, facc);
  hipLaunchKernelGGL(ktopk, dim3(NB), dim3(1024), 0, stream,
                     mine, num_pos, facc);
  hipLaunchKernelGGL(kfinal, dim3(1), dim3(1), 0, stream, facc, iacc, out);
}